// Round 6
// baseline (538.966 us; speedup 1.0000x reference)
//
#include <hip/hip_runtime.h>

// LSS view transform, round-14: round-4 pipeline (147.9us, best) fused into a
// single persistent kernel with manual device-scope grid barriers.
// out[b,c,cell] = sum_{(pix,d)->cell} img[b,c,pix] * dp[b,d,pix]
// Rationale: per-kernel cost model sums to ~50us vs 147.9 measured; the ~90us
// residual is attributed to 7 stream-serialized dispatch boundaries. This
// round converts them to ~1-2us in-kernel barriers. Algorithm, arithmetic and
// accumulation order are IDENTICAL to round 4 (chunked gather, sharded
// binning, readlane broadcasts). 512 blocks x 256 thr; __launch_bounds__(256,2)
// caps VGPR at 256 -> >=2 blocks/CU resident -> 512 co-resident, no deadlock.
constexpr int IMG_H = 48, IMG_W = 160;
constexpr int HW    = IMG_H * IMG_W;          // 7680
constexpr int BEV_H = 128, BEV_W = 128;
constexpr int NCELL = BEV_H * BEV_W;          // 16384 per batch
constexpr int C_DIM = 128, D_DIM = 64, B_DIM = 2;
constexpr int NCELL_TOT = B_DIM * NCELL;      // 32768
constexpr int NPIX_TOT  = B_DIM * HW;         // 15360
constexpr int NPTS      = NPIX_TOT * D_DIM;   // 983040
constexpr int MAX_ENTRIES = NPTS;
constexpr int CHUNK = 64;
constexpr int NSHARD = 16;
constexpr int G     = 512;                    // persistent grid (2 blocks/CU)
constexpr int CNT_BLOCKS = NPTS / 256;        // 3840 count units
constexpr int TRN_BLOCKS = (HW / 32) * (C_DIM / 32) * B_DIM;   // 1920
constexpr int UNT_TILES  = (NCELL / 32) * (C_DIM / 32) * B_DIM; // 4096
constexpr float X_MIN = -51.2f, Y_MIN = -51.2f;
constexpr float RES_X = 102.4f / 128.0f;
constexpr float RES_Y = 102.4f / 128.0f;

typedef _Float16 half2v __attribute__((ext_vector_type(2)));

// ---- ws layout (4-byte words) ----
constexpr size_t WS_IMG_T = 0;                                      // half[B*HW*C]
constexpr size_t WS_BAR   = WS_IMG_T + (size_t)B_DIM * HW * C_DIM / 2; // int[4] [memset]
constexpr size_t WS_HIST2 = WS_BAR + 4;                             // int[16*32768] [memset]
constexpr size_t WS_OUT_T = WS_HIST2 + (size_t)NSHARD * NCELL_TOT;  // float[32768*128] [memset]
constexpr size_t WS_HIST  = WS_OUT_T + (size_t)NCELL_TOT * C_DIM;   // int[32768]
constexpr size_t WS_OFFS  = WS_HIST + NCELL_TOT;                    // int[32769]+pad
constexpr size_t WS_BSUM  = WS_OFFS + NCELL_TOT + 4;                // int[128]
constexpr size_t WS_EKEY  = WS_BSUM + 128;                          // int[NPTS]
constexpr size_t WS_EW16  = WS_EKEY + MAX_ENTRIES;                  // ushort[NPTS]
constexpr size_t MEMSET_WORDS = 4 + (size_t)NSHARD * NCELL_TOT + (size_t)NCELL_TOT * C_DIM;

__device__ inline int point_shard(int tid) {
    return ((tid >> 2) + (tid >> 8)) & (NSHARD - 1);   // deterministic in tid
}

__device__ inline void make_ray(const float* __restrict__ K, int b, float gx, float gy,
                                float& rx, float& ry, float& rz) {
    const float* Kb = K + b * 9;
    const float a00 = Kb[0], a01 = Kb[1], a02 = Kb[2];
    const float a10 = Kb[3], a11 = Kb[4], a12 = Kb[5];
    const float a20 = Kb[6], a21 = Kb[7], a22 = Kb[8];
    const float det = a00 * (a11 * a22 - a12 * a21)
                    - a01 * (a10 * a22 - a12 * a20)
                    + a02 * (a10 * a21 - a11 * a20);
    const float inv = 1.0f / det;
    const float i00 =  (a11 * a22 - a12 * a21) * inv;
    const float i01 = -(a01 * a22 - a02 * a21) * inv;
    const float i02 =  (a01 * a12 - a02 * a11) * inv;
    const float i10 = -(a10 * a22 - a12 * a20) * inv;
    const float i11 =  (a00 * a22 - a02 * a20) * inv;
    const float i12 = -(a00 * a12 - a02 * a10) * inv;
    const float i20 =  (a10 * a21 - a11 * a20) * inv;
    const float i21 = -(a00 * a21 - a01 * a20) * inv;
    const float i22 =  (a00 * a11 - a01 * a10) * inv;
    rx = i00 * gx + i01 * gy + i02;
    ry = i10 * gx + i11 * gy + i12;
    rz = i20 * gx + i21 * gy + i22;
}

// Returns global cell id (b*NCELL + cell) or -1. tid = ((b*D + d)*HW + pix).
__device__ inline int point_gcell(int tid, const float* __restrict__ dv,
                                  const float* __restrict__ K,
                                  const float* __restrict__ T) {
    const int pix = tid % HW;
    const int bd  = tid / HW;
    const int d   = bd % D_DIM;
    const int b   = bd / D_DIM;
    const int h = pix / IMG_W, w = pix % IMG_W;
    float rx, ry, rz;
    make_ray(K, b, (float)w, (float)h, rx, ry, rz);
    const float* Tb = T + b * 16;
    const float dep = dv[d];                       // wave-uniform
    const float px = dep * rx, py = dep * ry, pz = dep * rz;
    const float x = Tb[0] * px + Tb[1] * py + Tb[2]  * pz + Tb[3];
    const float y = Tb[4] * px + Tb[5] * py + Tb[6]  * pz + Tb[7];
    const float z = Tb[8] * px + Tb[9] * py + Tb[10] * pz + Tb[11];
    const int bx = (int)((x - X_MIN) / RES_X);     // truncate-toward-zero == astype(int32)
    const int by = (int)((y - Y_MIN) / RES_Y);
    const bool valid = (bx >= 0) && (bx < BEV_W) && (by >= 0) && (by < BEV_H) && (z > 0.0f);
    return valid ? (b * NCELL + by * BEV_W + bx) : -1;
}

// Wave-run helpers: lanes are consecutive pixels -> equal-cell runs.
__device__ inline bool wave_runs(int gcell, int lane, int& run_len, int& leader_idx) {
    const int left = __shfl_up(gcell, 1);          // width 64
    const bool is_leader = (lane == 0) || (left != gcell);
    const unsigned long long lmask = __ballot(is_leader);
    const unsigned long long rest = (lane == 63) ? 0ULL : (lmask >> (lane + 1));
    const int f = __ffsll((unsigned long long)rest);   // 1+idx or 0
    run_len = f ? f : (64 - lane);
    const unsigned long long below =
        lmask & ((lane == 63) ? ~0ULL : ((1ULL << (lane + 1)) - 1ULL));
    leader_idx = 63 - __clzll((long long)below);
    return is_leader;
}

// Device-scope grid barrier (epoch-based). bar[0]=counter, bar[1]=epoch flag.
// Same pattern as ROCm cooperative-groups grid.sync: agent-scope atomics,
// release fence before arrival, acquire on observation.
__device__ inline void gsync(int* __restrict__ bar, int epoch) {
    __syncthreads();
    if (threadIdx.x == 0) {
        __threadfence();                                    // release (wb L2)
        if (__hip_atomic_fetch_add(&bar[0], 1, __ATOMIC_ACQ_REL,
                                   __HIP_MEMORY_SCOPE_AGENT) == G - 1) {
            __hip_atomic_store(&bar[0], 0, __ATOMIC_RELAXED, __HIP_MEMORY_SCOPE_AGENT);
            __hip_atomic_store(&bar[1], epoch, __ATOMIC_RELEASE, __HIP_MEMORY_SCOPE_AGENT);
        } else {
            while (__hip_atomic_load(&bar[1], __ATOMIC_ACQUIRE,
                                     __HIP_MEMORY_SCOPE_AGENT) < epoch)
                __builtin_amdgcn_s_sleep(4);
        }
    }
    __syncthreads();
}

__global__ __launch_bounds__(256, 2) void k_mega(
    const float* __restrict__ img, const float* __restrict__ dp,
    const float* __restrict__ dv, const float* __restrict__ K,
    const float* __restrict__ T,
    _Float16* __restrict__ img_t, int* __restrict__ bar,
    int* __restrict__ hist2, float* __restrict__ out_t,
    int* __restrict__ hist, int* __restrict__ offs, int* __restrict__ bsum,
    int* __restrict__ ekey, unsigned short* __restrict__ ew16,
    float* __restrict__ out)
{
    __shared__ float tile[32][33];
    __shared__ int ldsi[256];
    const int t = threadIdx.x;
    const int lane = t & 63;
    const int wave = t >> 6;

    // ---- P1: fused sharded count + transpose/fp16 (grid-stride units) ----
    for (int u = blockIdx.x; u < CNT_BLOCKS + TRN_BLOCKS; u += G) {
        if (u < CNT_BLOCKS) {
            const int tid = u * 256 + t;
            const int gcell = point_gcell(tid, dv, K, T);
            int run_len, leader_idx;
            const bool lead = wave_runs(gcell, lane, run_len, leader_idx);
            if (lead && gcell >= 0)
                atomicAdd(&hist2[(size_t)point_shard(tid) * NCELL_TOT + gcell], run_len);
        } else {
            const int bi = u - CNT_BLOCKS;
            const int px_t = bi % (HW / 32);
            const int c_t  = (bi / (HW / 32)) % (C_DIM / 32);
            const int b    = bi / ((HW / 32) * (C_DIM / 32));
            const int tx = t & 31, ty = t >> 5;            // (32,8)
            const int pix0 = px_t * 32, c0 = c_t * 32;
            __syncthreads();                               // tile reuse guard
            #pragma unroll
            for (int j = 0; j < 32; j += 8)
                tile[ty + j][tx] = img[((size_t)(b * C_DIM + c0 + ty + j)) * HW + pix0 + tx];
            __syncthreads();
            #pragma unroll
            for (int j = 0; j < 32; j += 8)
                img_t[((size_t)(b * HW + pix0 + ty + j)) * C_DIM + c0 + tx] =
                    (_Float16)tile[tx][ty + j];
        }
    }
    gsync(bar, 1);

    // ---- P2: reduce shards -> hist; hist2 becomes per-cell local prefix ----
    for (int cell = blockIdx.x * 256 + t; cell < NCELL_TOT; cell += G * 256) {
        int run = 0;
        #pragma unroll
        for (int sh = 0; sh < NSHARD; ++sh) {
            const size_t idx = (size_t)sh * NCELL_TOT + cell;
            const int c = hist2[idx];
            hist2[idx] = run;
            run += c;
        }
        hist[cell] = run;
    }
    gsync(bar, 2);

    // ---- P3A: per-tile (256 cells) exclusive scan, tile sums to bsum ----
    if (blockIdx.x < NCELL_TOT / 256) {
        const int cell = blockIdx.x * 256 + t;
        const int h = hist[cell];
        ldsi[t] = h;
        __syncthreads();
        #pragma unroll
        for (int off = 1; off < 256; off <<= 1) {
            const int v = (t >= off) ? ldsi[t - off] : 0;
            __syncthreads();
            ldsi[t] += v;
            __syncthreads();
        }
        offs[cell] = ldsi[t] - h;                          // tile-local exclusive
        if (t == 255) bsum[blockIdx.x] = ldsi[255];
    }
    gsync(bar, 3);

    // ---- P3B: block 0 scans the 128 tile sums ----
    if (blockIdx.x == 0) {
        const int v = (t < 128) ? bsum[t] : 0;
        ldsi[t] = v;
        __syncthreads();
        #pragma unroll
        for (int off = 1; off < 256; off <<= 1) {
            const int u2 = (t >= off) ? ldsi[t - off] : 0;
            __syncthreads();
            ldsi[t] += u2;
            __syncthreads();
        }
        if (t < 128) bsum[t] = ldsi[t] - v;                // exclusive
        if (t == 127) offs[NCELL_TOT] = ldsi[127];         // total entries
    }
    gsync(bar, 4);

    // ---- P3C: add tile base ----
    if (blockIdx.x < NCELL_TOT / 256)
        offs[blockIdx.x * 256 + t] += bsum[blockIdx.x];
    gsync(bar, 5);

    // ---- P4: fill entries (leader reserves span via offs + local cursor) ----
    for (int tid = blockIdx.x * 256 + t; tid < NPTS; tid += G * 256) {
        const int gcell = point_gcell(tid, dv, K, T);
        int run_len, leader_idx;
        const bool lead = wave_runs(gcell, lane, run_len, leader_idx);
        int base = 0;
        if (lead && gcell >= 0)
            base = offs[gcell]
                 + atomicAdd(&hist2[(size_t)point_shard(tid) * NCELL_TOT + gcell], run_len);
        base = __shfl(base, leader_idx);
        if (gcell >= 0) {
            const int slot = base + (lane - leader_idx);   // contiguous, coalesced
            const float p = dp[tid];                       // coalesced
            ekey[slot] = (gcell << 13) | (tid % HW);
            ew16[slot] = (unsigned short)__float2uint_rn(p * 65535.0f);
        }
    }
    gsync(bar, 6);

    // ---- P5: chunked gather (round-4 body; readlane broadcasts) ----
    {
        const int total = offs[NCELL_TOT];
        const int nch = (total + CHUNK - 1) >> 6;
        for (int ci = blockIdx.x * 4 + wave; ci < nch; ci += G * 4) {
            const int base = ci * CHUNK;
            const int eidx = min(base + lane, total - 1);
            const int   mykey = ekey[eidx];
            const float myw   = (base + lane < total)
                                ? (float)ew16[base + lane] * (1.0f / 65535.0f) : 0.0f;
            const int mywi = __float_as_int(myw);
            const int c2 = lane * 2;
            int prev = __builtin_amdgcn_readlane(mykey, 0) >> 13;
            float2 acc = make_float2(0.0f, 0.0f);

#define LOADG(g, V)                                                              \
    do {                                                                         \
        _Pragma("unroll")                                                        \
        for (int k = 0; k < 8; ++k) {                                            \
            const int key = __builtin_amdgcn_readlane(mykey, (g) * 8 + k);       \
            const int pix = key & 8191;                                          \
            const int bb  = key >> 27;                                           \
            V[k] = *reinterpret_cast<const half2v*>(                             \
                &img_t[((size_t)(bb * HW + pix)) * C_DIM + c2]);                 \
        }                                                                        \
    } while (0)

#define FLUSHP(cell)                                                             \
    do {                                                                         \
        float* o = &out_t[(size_t)(cell) * C_DIM + c2];                          \
        atomicAdd(o, acc.x);                                                     \
        atomicAdd(o + 1, acc.y);                                                 \
    } while (0)

#define ACCG(g, V)                                                               \
    do {                                                                         \
        _Pragma("unroll")                                                        \
        for (int k = 0; k < 8; ++k) {                                            \
            const int   key = __builtin_amdgcn_readlane(mykey, (g) * 8 + k);     \
            const float wgt =                                                    \
                __int_as_float(__builtin_amdgcn_readlane(mywi, (g) * 8 + k));    \
            const int gcell = key >> 13;                                         \
            if (gcell != prev) {                                                 \
                FLUSHP(prev);                                                    \
                acc = make_float2(0.0f, 0.0f);                                   \
                prev = gcell;                                                    \
            }                                                                    \
            acc.x = fmaf((float)V[k][0], wgt, acc.x);                            \
            acc.y = fmaf((float)V[k][1], wgt, acc.y);                            \
        }                                                                        \
    } while (0)

            half2v va[8], vb[8];
            LOADG(0, va);
            LOADG(1, vb);
            ACCG(0, va);
            LOADG(2, va);
            ACCG(1, vb);
            LOADG(3, vb);
            ACCG(2, va);
            LOADG(4, va);
            ACCG(3, vb);
            LOADG(5, vb);
            ACCG(4, va);
            LOADG(6, va);
            ACCG(5, vb);
            LOADG(7, vb);
            ACCG(6, va);
            ACCG(7, vb);
            FLUSHP(prev);
#undef LOADG
#undef FLUSHP
#undef ACCG
        }
    }
    gsync(bar, 7);

    // ---- P6: untranspose out_t[b][cell][c] -> out[b][c][cell] ----
    for (int u = blockIdx.x; u < UNT_TILES; u += G) {
        const int cell_t = u % (NCELL / 32);
        const int c_t    = (u / (NCELL / 32)) % (C_DIM / 32);
        const int b      = u / ((NCELL / 32) * (C_DIM / 32));
        const int tx = t & 31, ty = t >> 5;                // (32,8)
        const int cell0 = cell_t * 32, c0 = c_t * 32;
        const float* src = out_t + (size_t)b * NCELL * C_DIM;
        __syncthreads();                                   // tile reuse guard
        #pragma unroll
        for (int j = 0; j < 32; j += 8)
            tile[ty + j][tx] = src[((size_t)(cell0 + ty + j)) * C_DIM + c0 + tx];
        __syncthreads();
        #pragma unroll
        for (int j = 0; j < 32; j += 8)
            out[((size_t)(b * C_DIM + c0 + ty + j)) * NCELL + cell0 + tx] = tile[tx][ty + j];
    }
}

extern "C" void kernel_launch(void* const* d_in, const int* in_sizes, int n_in,
                              void* d_out, int out_size, void* d_ws, size_t ws_size,
                              hipStream_t stream) {
    const float* img = (const float*)d_in[0];
    const float* dp  = (const float*)d_in[1];
    const float* dv  = (const float*)d_in[2];
    const float* K   = (const float*)d_in[3];
    const float* T   = (const float*)d_in[4];
    float* out = (float*)d_out;

    _Float16* img_t = (_Float16*)d_ws;                  // WS_IMG_T == 0
    int*   bar    = (int*)d_ws + WS_BAR;
    int*   hist2  = (int*)d_ws + WS_HIST2;
    float* out_t  = (float*)d_ws + WS_OUT_T;
    int*   hist   = (int*)d_ws + WS_HIST;
    int*   offs   = (int*)d_ws + WS_OFFS;
    int*   bsum   = (int*)d_ws + WS_BSUM;
    int*   ekey   = (int*)d_ws + WS_EKEY;
    unsigned short* ew16 = (unsigned short*)((int*)d_ws + WS_EW16);
    (void)ws_size;

    // zero bar + hist2 + out_t in one contiguous memset (~18.9 MB)
    hipMemsetAsync(bar, 0, MEMSET_WORDS * sizeof(int), stream);

    k_mega<<<G, 256, 0, stream>>>(img, dp, dv, K, T, img_t, bar, hist2, out_t,
                                  hist, offs, bsum, ekey, ew16, out);
}

// Round 7
// 140.745 us; speedup vs baseline: 3.8294x; 3.8294x over previous
//
#include <hip/hip_runtime.h>

// LSS view transform, chunked-gather formulation, sharded + wave-run binning,
// cell-major atomic accumulator.
// out[b,c,cell] = sum_{(pix,d)->cell} img[b,c,pix] * dp[b,d,pix]
// Round-15 (base = round-12/147.9us; round-14 mega-kernel falsified barriers):
//  - dur_us includes a fixed ~45.5us harness poison fill (539 = 45.5+3.3+491
//    in round 14) -> controllable budget is ~102us, of which ~42us is 6
//    dispatch gaps. Attack: fewer dispatches, normal kernels.
//  - k_reduce + k_scan -> single k_scan_fused (decoupled lookback, 128 blocks,
//    packed status|value flags, wave-parallel 64-wide lookback). -2 nodes.
//  - k_chunk_gather: flushes to cells wholly owned by this chunk (not
//    continued across either boundary) are plain float2 stores; atomics only
//    for chunk-boundary cells (~65% of flushes -> ~35% fewer atomic dwords).
constexpr int IMG_H = 48, IMG_W = 160;
constexpr int HW    = IMG_H * IMG_W;          // 7680
constexpr int BEV_H = 128, BEV_W = 128;
constexpr int NCELL = BEV_H * BEV_W;          // 16384 per batch
constexpr int C_DIM = 128, D_DIM = 64, B_DIM = 2;
constexpr int NCELL_TOT = B_DIM * NCELL;      // 32768
constexpr int NPIX_TOT  = B_DIM * HW;         // 15360
constexpr int NPTS      = NPIX_TOT * D_DIM;   // 983040
constexpr int MAX_ENTRIES = NPTS;
constexpr int CHUNK = 64;
constexpr int WAVES_PER_BLK = 4;
constexpr int NSHARD = 16;
constexpr int CNT_BLOCKS = NPTS / 256;        // 3840
constexpr int TRN_BLOCKS = (HW / 32) * (C_DIM / 32) * B_DIM;  // 1920
constexpr int SCAN_BLOCKS = NCELL_TOT / 256;  // 128
constexpr float X_MIN = -51.2f, Y_MIN = -51.2f;
constexpr float RES_X = 102.4f / 128.0f;
constexpr float RES_Y = 102.4f / 128.0f;

typedef _Float16 half2v __attribute__((ext_vector_type(2)));

// ---- ws layout (4-byte words), ~28.8 MB total ----
constexpr size_t WS_IMG_T = 0;                                      // half[B*HW*C]
constexpr size_t WS_FLAGS = WS_IMG_T + (size_t)B_DIM * HW * C_DIM / 2;  // uint[128] [memset]
constexpr size_t WS_HIST2 = WS_FLAGS + 128;                         // int[16*32768] [memset]
constexpr size_t WS_OUT_T = WS_HIST2 + (size_t)NSHARD * NCELL_TOT;  // float[32768*128] [memset, adjacent]
constexpr size_t WS_OFFS  = WS_OUT_T + (size_t)NCELL_TOT * C_DIM;   // int[32769]+pad
constexpr size_t WS_EKEY  = WS_OFFS + NCELL_TOT + 4;                // int[NPTS]
constexpr size_t WS_EW16  = WS_EKEY + MAX_ENTRIES;                  // ushort[NPTS]
constexpr size_t MEMSET_WORDS = 128 + (size_t)NSHARD * NCELL_TOT + (size_t)NCELL_TOT * C_DIM;

__device__ inline int point_shard(int tid) {
    return ((tid >> 2) + (tid >> 8)) & (NSHARD - 1);   // deterministic in tid
}

__device__ inline void make_ray(const float* __restrict__ K, int b, float gx, float gy,
                                float& rx, float& ry, float& rz) {
    const float* Kb = K + b * 9;
    const float a00 = Kb[0], a01 = Kb[1], a02 = Kb[2];
    const float a10 = Kb[3], a11 = Kb[4], a12 = Kb[5];
    const float a20 = Kb[6], a21 = Kb[7], a22 = Kb[8];
    const float det = a00 * (a11 * a22 - a12 * a21)
                    - a01 * (a10 * a22 - a12 * a20)
                    + a02 * (a10 * a21 - a11 * a20);
    const float inv = 1.0f / det;
    const float i00 =  (a11 * a22 - a12 * a21) * inv;
    const float i01 = -(a01 * a22 - a02 * a21) * inv;
    const float i02 =  (a01 * a12 - a02 * a11) * inv;
    const float i10 = -(a10 * a22 - a12 * a20) * inv;
    const float i11 =  (a00 * a22 - a02 * a20) * inv;
    const float i12 = -(a00 * a12 - a02 * a10) * inv;
    const float i20 =  (a10 * a21 - a11 * a20) * inv;
    const float i21 = -(a00 * a21 - a01 * a20) * inv;
    const float i22 =  (a00 * a11 - a01 * a10) * inv;
    rx = i00 * gx + i01 * gy + i02;
    ry = i10 * gx + i11 * gy + i12;
    rz = i20 * gx + i21 * gy + i22;
}

// Returns global cell id (b*NCELL + cell) or -1. tid = ((b*D + d)*HW + pix).
__device__ inline int point_gcell(int tid, const float* __restrict__ dv,
                                  const float* __restrict__ K,
                                  const float* __restrict__ T) {
    const int pix = tid % HW;
    const int bd  = tid / HW;
    const int d   = bd % D_DIM;
    const int b   = bd / D_DIM;
    const int h = pix / IMG_W, w = pix % IMG_W;
    float rx, ry, rz;
    make_ray(K, b, (float)w, (float)h, rx, ry, rz);
    const float* Tb = T + b * 16;
    const float dep = dv[d];                       // wave-uniform
    const float px = dep * rx, py = dep * ry, pz = dep * rz;
    const float x = Tb[0] * px + Tb[1] * py + Tb[2]  * pz + Tb[3];
    const float y = Tb[4] * px + Tb[5] * py + Tb[6]  * pz + Tb[7];
    const float z = Tb[8] * px + Tb[9] * py + Tb[10] * pz + Tb[11];
    const int bx = (int)((x - X_MIN) / RES_X);     // truncate-toward-zero == astype(int32)
    const int by = (int)((y - Y_MIN) / RES_Y);
    const bool valid = (bx >= 0) && (bx < BEV_W) && (by >= 0) && (by < BEV_H) && (z > 0.0f);
    return valid ? (b * NCELL + by * BEV_W + bx) : -1;
}

// Wave-run helpers: lanes are consecutive pixels -> equal-cell runs.
__device__ inline bool wave_runs(int gcell, int lane, int& run_len, int& leader_idx) {
    const int left = __shfl_up(gcell, 1);          // width 64
    const bool is_leader = (lane == 0) || (left != gcell);
    const unsigned long long lmask = __ballot(is_leader);
    const unsigned long long rest = (lane == 63) ? 0ULL : (lmask >> (lane + 1));
    const int f = __ffsll((unsigned long long)rest);   // 1+idx or 0
    run_len = f ? f : (64 - lane);
    const unsigned long long below =
        lmask & ((lane == 63) ? ~0ULL : ((1ULL << (lane + 1)) - 1ULL));
    leader_idx = 63 - __clzll((long long)below);
    return is_leader;
}

// ---- K1: fused {sharded count (blocks 0..3839)} + {transpose/fp16 (3840..5759)} ----
__global__ __launch_bounds__(256) void k_prep(const float* __restrict__ img,
                                              _Float16* __restrict__ img_t,
                                              const float* __restrict__ dv,
                                              const float* __restrict__ K,
                                              const float* __restrict__ T,
                                              int* __restrict__ hist2) {
    __shared__ float tile[32][33];
    if (blockIdx.x < CNT_BLOCKS) {
        const int tid = blockIdx.x * 256 + threadIdx.x;   // < NPTS (exact)
        const int gcell = point_gcell(tid, dv, K, T);
        const int lane = threadIdx.x & 63;
        int run_len, leader_idx;
        const bool lead = wave_runs(gcell, lane, run_len, leader_idx);
        if (lead && gcell >= 0)
            atomicAdd(&hist2[(size_t)point_shard(tid) * NCELL_TOT + gcell], run_len);
    } else {
        const int bi = blockIdx.x - CNT_BLOCKS;
        const int px_t = bi % (HW / 32);
        const int c_t  = (bi / (HW / 32)) % (C_DIM / 32);
        const int b    = bi / ((HW / 32) * (C_DIM / 32));
        const int tx = threadIdx.x & 31, ty = threadIdx.x >> 5;   // (32,8)
        const int pix0 = px_t * 32, c0 = c_t * 32;
        #pragma unroll
        for (int j = 0; j < 32; j += 8)
            tile[ty + j][tx] = img[((size_t)(b * C_DIM + c0 + ty + j)) * HW + pix0 + tx];
        __syncthreads();
        #pragma unroll
        for (int j = 0; j < 32; j += 8)
            img_t[((size_t)(b * HW + pix0 + ty + j)) * C_DIM + c0 + tx] =
                (_Float16)tile[tx][ty + j];
    }
}

// ---- K2: fused shard-reduce + global exclusive scan (decoupled lookback).
// One thread = one cell: 16-shard reduce + in-place local prefix; block-scan;
// flag word = status[31:30] (1=aggregate, 2=inclusive) | value[29:0].
// Totals < 2^20 so the pack is safe. Wave-parallel 64-wide lookback.
__global__ __launch_bounds__(256) void k_scan_fused(int* __restrict__ hist2,
                                                    int* __restrict__ offs,
                                                    unsigned* __restrict__ flags) {
    __shared__ int lds[256];
    __shared__ int s_base;
    const int b = blockIdx.x;                      // 128 blocks
    const int t = threadIdx.x;                     // 256 threads
    const int cell = b * 256 + t;
    // shard reduce + in-place local exclusive prefix (coalesced sweeps)
    int run = 0;
    #pragma unroll
    for (int sh = 0; sh < NSHARD; ++sh) {
        const size_t idx = (size_t)sh * NCELL_TOT + cell;
        const int c = hist2[idx];
        hist2[idx] = run;
        run += c;
    }
    const int h = run;                             // cell total
    // inclusive block scan
    lds[t] = h;
    __syncthreads();
    #pragma unroll
    for (int off = 1; off < 256; off <<= 1) {
        const int v = (t >= off) ? lds[t - off] : 0;
        __syncthreads();
        lds[t] += v;
        __syncthreads();
    }
    const int incl = lds[t];
    const int S = lds[255];                        // block aggregate
    if (t == 0) {
        const unsigned w = (((b == 0) ? 2u : 1u) << 30) | (unsigned)S;
        __hip_atomic_store(&flags[b], w, __ATOMIC_RELEASE, __HIP_MEMORY_SCOPE_AGENT);
        if (b == 0) s_base = 0;
    }
    if (b > 0 && t < 64) {                         // wave-0 lookback
        int sum = 0;
        int p = b - 1;
        bool done = false;
        while (!done) {
            const int idx = p - t;
            unsigned w;
            if (idx >= 0) {
                do {
                    w = __hip_atomic_load(&flags[idx], __ATOMIC_ACQUIRE,
                                          __HIP_MEMORY_SCOPE_AGENT);
                } while ((w >> 30) == 0);
            } else {
                w = 2u << 30;                      // virtual predecessor: incl 0
            }
            const unsigned long long m2 = __ballot((w >> 30) == 2u);
            const int first2 = __ffsll(m2) - 1;    // nearest inclusive pred (lane idx)
            const int limit = (first2 < 0) ? 63 : first2;
            int contrib = (t <= limit && idx >= 0) ? (int)(w & 0x3FFFFFFFu) : 0;
            #pragma unroll
            for (int o = 32; o > 0; o >>= 1) contrib += __shfl_down(contrib, o);
            sum += __shfl(contrib, 0);
            if (first2 >= 0) done = true;
            else p -= 64;
        }
        if (t == 0) {
            s_base = sum;
            const unsigned w2 = (2u << 30) | (unsigned)(sum + S);
            __hip_atomic_store(&flags[b], w2, __ATOMIC_RELEASE, __HIP_MEMORY_SCOPE_AGENT);
        }
    }
    __syncthreads();
    const int base = s_base;
    offs[cell] = base + incl - h;                  // global exclusive prefix
    if (cell == NCELL_TOT - 1) offs[NCELL_TOT] = base + S;
}

// ---- K3: fill entries; leader reserves span via offs + local shard cursor ----
__global__ __launch_bounds__(256) void k_fill(const float* __restrict__ dp,
                                              const float* __restrict__ dv,
                                              const float* __restrict__ K,
                                              const float* __restrict__ T,
                                              const int* __restrict__ offs,
                                              int* __restrict__ cursor2,   // = hist2 (local prefix)
                                              int* __restrict__ ekey,
                                              unsigned short* __restrict__ ew16) {
    const int tid = blockIdx.x * 256 + threadIdx.x;   // < NPTS (exact grid)
    const int gcell = point_gcell(tid, dv, K, T);
    const int lane = threadIdx.x & 63;
    int run_len, leader_idx;
    const bool lead = wave_runs(gcell, lane, run_len, leader_idx);
    int base = 0;
    if (lead && gcell >= 0)
        base = offs[gcell]
             + atomicAdd(&cursor2[(size_t)point_shard(tid) * NCELL_TOT + gcell], run_len);
    base = __shfl(base, leader_idx);                  // broadcast my run's base
    if (gcell < 0) return;
    const int slot = base + (lane - leader_idx);      // contiguous, coalesced writes
    const float p = dp[tid];                          // tid == ((b*D+d)*HW+pix): coalesced
    ekey[slot] = (gcell << 13) | (tid % HW);
    ew16[slot] = (unsigned short)__float2uint_rn(p * 65535.0f);
}

// ---- K4: chunked segmented reduction. 4 waves/block, wave = one 64-entry
// chunk, thread = 2 channels. readlane broadcasts (SGPR path). Flush:
// cells wholly owned by this chunk -> plain float2 store; cells continued
// across a chunk boundary -> atomicAdd. Accumulation order as round 12.
__global__ __launch_bounds__(256) void k_chunk_gather(
    const _Float16* __restrict__ img_t,
    const int* __restrict__ offs,     // offs[NCELL_TOT] = total entry count
    const int* __restrict__ ekey,
    const unsigned short* __restrict__ ew16,
    float* __restrict__ out_t)
{
    const int total = offs[NCELL_TOT];
    const int wave  = threadIdx.x >> 6;
    const int lane  = threadIdx.x & 63;
    const int base  = (blockIdx.x * WAVES_PER_BLK + wave) * CHUNK;
    if (base >= total) return;

    // per-lane entry fetch (coalesced); pad = dup last key, weight 0
    const int eidx = min(base + lane, total - 1);
    const int   mykey = ekey[eidx];
    const float myw   = (base + lane < total)
                        ? (float)ew16[base + lane] * (1.0f / 65535.0f) : 0.0f;
    const int mywi = __float_as_int(myw);

    const int c2 = lane * 2;                          // channels c2, c2+1
    const int fc    = __builtin_amdgcn_readlane(mykey, 0) >> 13;   // first cell
    const int lcell = __builtin_amdgcn_readlane(mykey, 63) >> 13;  // last cell
    // boundary-continuation flags (uniform scalar loads, broadcast by cache)
    const bool shared_first = (base > 0) && ((ekey[base - 1] >> 13) == fc);
    const bool shared_last  = (base + CHUNK < total) && ((ekey[base + CHUNK] >> 13) == lcell);

    int prev = fc;
    float2 acc = make_float2(0.0f, 0.0f);

#define LOADG(g, V)                                                              \
    do {                                                                         \
        _Pragma("unroll")                                                        \
        for (int k = 0; k < 8; ++k) {                                            \
            const int key = __builtin_amdgcn_readlane(mykey, (g) * 8 + k);       \
            const int pix = key & 8191;                                          \
            const int bb  = key >> 27;                                           \
            V[k] = *reinterpret_cast<const half2v*>(                             \
                &img_t[((size_t)(bb * HW + pix)) * C_DIM + c2]);                 \
        }                                                                        \
    } while (0)

#define FLUSHP(cell)                                                             \
    do {                                                                         \
        float* o = &out_t[(size_t)(cell) * C_DIM + c2];                          \
        const bool shared_ = ((cell) == fc && shared_first) ||                   \
                             ((cell) == lcell && shared_last);                   \
        if (shared_) {                                                           \
            atomicAdd(o, acc.x);                                                 \
            atomicAdd(o + 1, acc.y);                                             \
        } else {                                                                 \
            *reinterpret_cast<float2*>(o) = acc;  /* exclusive owner */          \
        }                                                                        \
    } while (0)

#define ACCG(g, V)                                                               \
    do {                                                                         \
        _Pragma("unroll")                                                        \
        for (int k = 0; k < 8; ++k) {                                            \
            const int   key = __builtin_amdgcn_readlane(mykey, (g) * 8 + k);     \
            const float wgt =                                                    \
                __int_as_float(__builtin_amdgcn_readlane(mywi, (g) * 8 + k));    \
            const int gcell = key >> 13;                                         \
            if (gcell != prev) {                      /* scalar branch */        \
                FLUSHP(prev);                                                    \
                acc = make_float2(0.0f, 0.0f);                                   \
                prev = gcell;                                                    \
            }                                                                    \
            acc.x = fmaf((float)V[k][0], wgt, acc.x);                            \
            acc.y = fmaf((float)V[k][1], wgt, acc.y);                            \
        }                                                                        \
    } while (0)

    half2v va[8], vb[8];
    // modulo-2 software pipeline over 8 groups of 8 entries (CHUNK=64)
    LOADG(0, va);
    LOADG(1, vb);
    ACCG(0, va);
    LOADG(2, va);
    ACCG(1, vb);
    LOADG(3, vb);
    ACCG(2, va);
    LOADG(4, va);
    ACCG(3, vb);
    LOADG(5, vb);
    ACCG(4, va);
    LOADG(6, va);
    ACCG(5, vb);
    LOADG(7, vb);
    ACCG(6, va);
    ACCG(7, vb);
    FLUSHP(prev);

#undef LOADG
#undef FLUSHP
#undef ACCG
}

// ---- K5: untranspose out_t[b][cell][c] -> out[b][c][cell] ----
__global__ __launch_bounds__(256) void k_untranspose(const float* __restrict__ out_t,
                                                     float* __restrict__ out) {
    __shared__ float tile[32][33];
    const int b = blockIdx.z;
    const int tx = threadIdx.x, ty = threadIdx.y;      // block (32, 8)
    const int cell0 = blockIdx.x * 32, c0 = blockIdx.y * 32;
    const float* src = out_t + (size_t)b * NCELL * C_DIM;
    #pragma unroll
    for (int j = 0; j < 32; j += 8)                    // read: c contiguous
        tile[ty + j][tx] = src[((size_t)(cell0 + ty + j)) * C_DIM + c0 + tx];
    __syncthreads();
    #pragma unroll
    for (int j = 0; j < 32; j += 8)                    // write: cell contiguous
        out[((size_t)(b * C_DIM + c0 + ty + j)) * NCELL + cell0 + tx] = tile[tx][ty + j];
}

extern "C" void kernel_launch(void* const* d_in, const int* in_sizes, int n_in,
                              void* d_out, int out_size, void* d_ws, size_t ws_size,
                              hipStream_t stream) {
    const float* img = (const float*)d_in[0];
    const float* dp  = (const float*)d_in[1];
    const float* dv  = (const float*)d_in[2];
    const float* K   = (const float*)d_in[3];
    const float* T   = (const float*)d_in[4];
    float* out = (float*)d_out;

    _Float16* img_t = (_Float16*)d_ws;                  // WS_IMG_T == 0
    unsigned* flags = (unsigned*)((int*)d_ws + WS_FLAGS);
    int*   hist2  = (int*)d_ws + WS_HIST2;
    float* out_t  = (float*)d_ws + WS_OUT_T;
    int*   offs   = (int*)d_ws + WS_OFFS;
    int*   ekey   = (int*)d_ws + WS_EKEY;
    unsigned short* ew16 = (unsigned short*)((int*)d_ws + WS_EW16);
    (void)ws_size;

    // zero flags + hist2 + out_t in one contiguous memset (~18.9 MB)
    hipMemsetAsync(flags, 0, MEMSET_WORDS * sizeof(int), stream);

    k_prep<<<CNT_BLOCKS + TRN_BLOCKS, 256, 0, stream>>>(img, img_t, dv, K, T, hist2);
    k_scan_fused<<<SCAN_BLOCKS, 256, 0, stream>>>(hist2, offs, flags);
    k_fill<<<NPTS / 256, 256, 0, stream>>>(dp, dv, K, T, offs, hist2, ekey, ew16);
    constexpr int GATHER_BLOCKS = MAX_ENTRIES / (CHUNK * WAVES_PER_BLK);
    k_chunk_gather<<<GATHER_BLOCKS, 256, 0, stream>>>(img_t, offs, ekey, ew16, out_t);
    k_untranspose<<<dim3(NCELL / 32, C_DIM / 32, B_DIM), dim3(32, 8), 0, stream>>>(
        out_t, out);
}